// Round 7
// baseline (92.424 us; speedup 1.0000x reference)
//
#include <hip/hip_runtime.h>
#include <hip/hip_bf16.h>
#include <math.h>
#include <cstdint>

#define NUSER 16384   // B*U
#define BB    64
#define UU    256
#define SSLOT 64
#define HD    256
#define KTOT  320     // 64 server slots + 256 user slots
#define DEGS  8
#define DEGU  16

typedef __attribute__((ext_vector_type(8))) short short8;
typedef __attribute__((ext_vector_type(4))) float f32x4;

static __device__ __forceinline__ __hip_bfloat16 f2b(float x) { return __float2bfloat16(x); }
static __device__ __forceinline__ unsigned pack2(float x, float y) {
  union { __hip_bfloat16 h[2]; unsigned u; } cv;
  cv.h[0] = f2b(x); cv.h[1] = f2b(y);
  return cv.u;
}

// ---------------------------------------------------------------------------
// K1: prep. blocks 0..63: zero own MSU row + scatter 1.0s + connS bitmask.
//           blocks 64..319: weight transposes to bf16.
// ---------------------------------------------------------------------------
__global__ __launch_bounds__(256) void k_prep(
    const int* __restrict__ dst_u2s, const int* __restrict__ dst_u2u,
    const float* __restrict__ oW2, const float* __restrict__ sW2,
    const float* __restrict__ sW3,
    unsigned long long* __restrict__ connS, unsigned short* __restrict__ MSU,
    __hip_bfloat16* __restrict__ W2T_o, __hip_bfloat16* __restrict__ W2T_s,
    __hip_bfloat16* __restrict__ W3T_s) {
  const int blk = blockIdx.x, t = threadIdx.x;
  if (blk < 64) {
    const int u = blk * 256 + t;
    uint4* row4 = (uint4*)(MSU + (size_t)u * KTOT);
    uint4 z = {0, 0, 0, 0};
    #pragma unroll
    for (int i = 0; i < 40; ++i) row4[i] = z;
    unsigned long long ms = 0ull;
    #pragma unroll
    for (int i = 0; i < DEGS; ++i) {
      int slot = dst_u2s[u * DEGS + i] & 63;
      ms |= 1ull << slot;
      MSU[(size_t)u * KTOT + slot] = 0x3F80;      // bf16 1.0
    }
    connS[u] = ms;
    #pragma unroll
    for (int i = 0; i < DEGU; ++i) {
      int slot = dst_u2u[u * DEGU + i] & 255;
      MSU[(size_t)u * KTOT + 64 + slot] = 0x3F80;
    }
  } else {
    const int n = blk - 64;
    W2T_o[n * HD + t] = f2b(oW2[t * HD + n]);
    W2T_s[n * HD + t] = f2b(sW2[t * HD + n]);
    if (n < SSLOT) W3T_s[n * HD + t] = f2b(sW3[t * SSLOT + n]);
  }
}

// ---------------------------------------------------------------------------
// K2: per-slot partial layer-1 products, bf16. grid (320 slots, 8 b-chunks).
// ---------------------------------------------------------------------------
__global__ __launch_bounds__(256) void k_pq(
    const float* __restrict__ xu, const float* __restrict__ xs,
    const float* __restrict__ oW1, const float* __restrict__ sW1,
    __hip_bfloat16* __restrict__ P_o, __hip_bfloat16* __restrict__ P_s,
    __hip_bfloat16* __restrict__ Q_o, __hip_bfloat16* __restrict__ Q_s) {
  const int t = threadIdx.x;
  const int wg = blockIdx.x;            // 0..63 server slots, 64..319 user slots
  const int b0 = blockIdx.y * 8;
  __shared__ float lx[8 * 16];
  const bool isS = wg < SSLOT;
  const int slot = isS ? wg : wg - SSLOT;
  if (t < 8 * 16) {
    int b = b0 + (t >> 4), d = t & 15;
    lx[t] = isS ? xs[(b * SSLOT + slot) * 16 + d] : xu[(b * UU + slot) * 16 + d];
  }
  __syncthreads();
  float wo[16], wsv[16];
  const int rbase = isS ? slot * 16 : SSLOT * 16 + slot * 16;
  #pragma unroll
  for (int d = 0; d < 16; ++d) {
    wo[d] = oW1[(rbase + d) * HD + t];
    wsv[d] = sW1[(rbase + d) * HD + t];
  }
  __hip_bfloat16* Ro = isS ? P_o : Q_o;
  __hip_bfloat16* Rs = isS ? P_s : Q_s;
  const int rows = isS ? SSLOT : UU;
  #pragma unroll
  for (int bi = 0; bi < 8; ++bi) {
    float ao = 0.f, as = 0.f;
    #pragma unroll
    for (int q = 0; q < 4; ++q) {
      float4 x4 = *(const float4*)&lx[bi * 16 + q * 4];
      ao = fmaf(x4.x, wo[q*4+0], ao); as = fmaf(x4.x, wsv[q*4+0], as);
      ao = fmaf(x4.y, wo[q*4+1], ao); as = fmaf(x4.y, wsv[q*4+1], as);
      ao = fmaf(x4.z, wo[q*4+2], ao); as = fmaf(x4.z, wsv[q*4+2], as);
      ao = fmaf(x4.w, wo[q*4+3], ao); as = fmaf(x4.w, wsv[q*4+3], as);
    }
    Ro[((b0 + bi) * rows + slot) * HD + t] = f2b(ao);
    Rs[((b0 + bi) * rows + slot) * HD + t] = f2b(as);
  }
}

// ---------------------------------------------------------------------------
// K3: transpose P,Q -> PQT[b][n][320] (n-major, k-contiguous) via LDS.
// ---------------------------------------------------------------------------
__global__ __launch_bounds__(256) void k_tr(
    const __hip_bfloat16* __restrict__ P_o, const __hip_bfloat16* __restrict__ P_s,
    const __hip_bfloat16* __restrict__ Q_o, const __hip_bfloat16* __restrict__ Q_s,
    __hip_bfloat16* __restrict__ PQT_o, __hip_bfloat16* __restrict__ PQT_s) {
  const int b = blockIdx.x, mlp = blockIdx.y, nc = blockIdx.z;
  const int n0 = nc * 64;
  const int t = threadIdx.x;
  const __hip_bfloat16* P = mlp ? P_s : P_o;
  const __hip_bfloat16* Q = mlp ? Q_s : Q_o;
  __hip_bfloat16* PQT = mlp ? PQT_s : PQT_o;
  __shared__ __align__(16) short lds[64 * 72];
  for (int kt = 0; kt < 5; ++kt) {
    const __hip_bfloat16* src = (kt == 0) ? (P + (size_t)(b * SSLOT) * HD)
                                          : (Q + (size_t)(b * UU + (kt - 1) * 64) * HD);
    const int kout = (kt == 0) ? 0 : 64 + (kt - 1) * 64;
    #pragma unroll
    for (int i = 0; i < 2; ++i) {
      int c = t + i * 256;
      int row = c >> 3, cc = c & 7;
      *(short8*)&lds[row * 72 + cc * 8] =
          *(const short8*)(src + (size_t)row * HD + n0 + cc * 8);
    }
    __syncthreads();
    #pragma unroll
    for (int i = 0; i < 2; ++i) {
      int c = t + i * 256;
      int nrow = c >> 3, kc = c & 7;
      short8 v;
      #pragma unroll
      for (int e = 0; e < 8; ++e) v[e] = lds[(kc * 8 + e) * 72 + nrow];
      *(short8*)(PQT + (size_t)(b * 256 + n0 + nrow) * KTOT + kout + kc * 8) = v;
    }
    __syncthreads();
  }
}

// ---------------------------------------------------------------------------
// K4: fused mask-GEMM (h1) -> layer-2 GEMM -> heads.
// grid (512 u-tiles of 32, 2 mlps); 4 waves; A-fragments straight from L2.
// LDS: h1 tile 16 KB + partials 1 KB -> high occupancy.
// ---------------------------------------------------------------------------
__global__ __launch_bounds__(256) void k_fused(
    const unsigned short* __restrict__ MSU,
    const __hip_bfloat16* __restrict__ PQT_o, const __hip_bfloat16* __restrict__ PQT_s,
    const float* __restrict__ ob1, const float* __restrict__ sb1,
    const __hip_bfloat16* __restrict__ W2T_o, const __hip_bfloat16* __restrict__ W2T_s,
    const float* __restrict__ ob2, const float* __restrict__ sb2,
    const float* __restrict__ oW3, const float* __restrict__ ob3,
    const __hip_bfloat16* __restrict__ W3T_s, const float* __restrict__ sb3,
    const unsigned long long* __restrict__ connS,
    float* __restrict__ out) {
  const int mlp = blockIdx.y;
  const int x = blockIdx.x;
  const int blk = (x & 7) * 64 + (x >> 3);      // XCD-affine, bijective (512%8==0)
  const int u0 = blk * 32;
  const int b = u0 >> 8;
  const int t = threadIdx.x, lane = t & 63, wid = t >> 6;
  const int lo = lane & 15, hi = lane >> 4;

  const __hip_bfloat16* PQT = mlp ? PQT_s : PQT_o;
  const __hip_bfloat16* W2T = mlp ? W2T_s : W2T_o;
  const float* b1 = mlp ? sb1 : ob1;
  const float* b2 = mlp ? sb2 : ob2;

  __shared__ __align__(16) char lds[17408];
  short* h1 = (short*)lds;               // [32 u][256 n] swizzled (16 KB), reused as sel
  float* part = (float*)(lds + 16384);   // [4][32][2] (1 KB)

  // ---- phase 1: h1 = relu(b1 + mask @ PQT^T); A,B from global (L2) ----
  f32x4 acc[2][4] = {};
  #pragma unroll
  for (int kt = 0; kt < 10; ++kt) {
    short8 af[2], bf[4];
    #pragma unroll
    for (int rb = 0; rb < 2; ++rb) {
      int row = rb * 16 + lo;
      af[rb] = *(const short8*)(MSU + (size_t)(u0 + row) * KTOT + kt * 32 + hi * 8);
    }
    #pragma unroll
    for (int cb = 0; cb < 4; ++cb) {
      int n = wid * 64 + cb * 16 + lo;
      bf[cb] = *(const short8*)(PQT + (size_t)(b * 256 + n) * KTOT + kt * 32 + hi * 8);
    }
    #pragma unroll
    for (int rb = 0; rb < 2; ++rb)
      #pragma unroll
      for (int cb = 0; cb < 4; ++cb)
        acc[rb][cb] = __builtin_amdgcn_mfma_f32_16x16x32_bf16(af[rb], bf[cb], acc[rb][cb], 0, 0, 0);
  }
  // epilogue-1: bias + relu -> h1 LDS (bf16, swizzled)
  #pragma unroll
  for (int cb = 0; cb < 4; ++cb) {
    int n = wid * 64 + cb * 16 + lo;
    float bv = b1[n];
    #pragma unroll
    for (int rb = 0; rb < 2; ++rb)
      #pragma unroll
      for (int j = 0; j < 4; ++j) {
        int row = rb * 16 + hi * 4 + j;
        float v = fmaxf(acc[rb][cb][j] + bv, 0.f);
        h1[row * 256 + ((n >> 3) ^ (row & 7)) * 8 + (n & 7)] = (short)pack2(v, 0.f);
      }
  }
  __syncthreads();

  // ---- phase 2: h2pre = h1 @ W2 (B from L2) ----
  f32x4 acc2[2][4] = {};
  #pragma unroll
  for (int ks = 0; ks < 8; ++ks) {
    short8 af[2], bf[4];
    #pragma unroll
    for (int rb = 0; rb < 2; ++rb) {
      int row = rb * 16 + lo;
      int ca = ks * 4 + hi;
      af[rb] = *(const short8*)&h1[row * 256 + (ca ^ (row & 7)) * 8];
    }
    #pragma unroll
    for (int cb = 0; cb < 4; ++cb) {
      int n = wid * 64 + cb * 16 + lo;
      bf[cb] = *(const short8*)(W2T + (size_t)n * HD + ks * 32 + hi * 8);
    }
    #pragma unroll
    for (int rb = 0; rb < 2; ++rb)
      #pragma unroll
      for (int cb = 0; cb < 4; ++cb)
        acc2[rb][cb] = __builtin_amdgcn_mfma_f32_16x16x32_bf16(af[rb], bf[cb], acc2[rb][cb], 0, 0, 0);
  }

  // ---- heads ----
  if (mlp == 0) {
    float p0[2][4] = {}, p1[2][4] = {};
    #pragma unroll
    for (int cb = 0; cb < 4; ++cb) {
      int n = wid * 64 + cb * 16 + lo;
      float bs = b2[n], w0 = oW3[2 * n], w1 = oW3[2 * n + 1];
      #pragma unroll
      for (int rb = 0; rb < 2; ++rb)
        #pragma unroll
        for (int j = 0; j < 4; ++j) {
          float sig = 1.0f / (1.0f + __expf(-(acc2[rb][cb][j] + bs)));
          p0[rb][j] = fmaf(sig, w0, p0[rb][j]);
          p1[rb][j] = fmaf(sig, w1, p1[rb][j]);
        }
    }
    #pragma unroll
    for (int rb = 0; rb < 2; ++rb)
      #pragma unroll
      for (int j = 0; j < 4; ++j) {
        #pragma unroll
        for (int off = 1; off < 16; off <<= 1) {
          p0[rb][j] += __shfl_xor(p0[rb][j], off, 64);
          p1[rb][j] += __shfl_xor(p1[rb][j], off, 64);
        }
        if (lo == 0) {
          int row = rb * 16 + hi * 4 + j;
          part[wid * 64 + row * 2 + 0] = p0[rb][j];
          part[wid * 64 + row * 2 + 1] = p1[rb][j];
        }
      }
    __syncthreads();
    if (t < 32) {
      float q0 = part[t * 2] + part[64 + t * 2] + part[128 + t * 2] + part[192 + t * 2] + ob3[0];
      float q1 = part[t * 2 + 1] + part[64 + t * 2 + 1] + part[128 + t * 2 + 1] + part[192 + t * 2 + 1] + ob3[1];
      float m2 = fmaxf(q0, q1);
      float e0 = __expf(q0 - m2), e1 = __expf(q1 - m2);
      float iv = 1.0f / (e0 + e1);
      float2 r; r.x = e0 * iv; r.y = e1 * iv;
      *(float2*)(out + (size_t)(u0 + t) * 2) = r;
    }
  } else {
    __syncthreads();                      // all phase-2 h1 reads complete
    short* sel = h1;
    #pragma unroll
    for (int cb = 0; cb < 4; ++cb) {
      int n = wid * 64 + cb * 16 + lo;
      float bs = b2[n];
      #pragma unroll
      for (int rb = 0; rb < 2; ++rb)
        #pragma unroll
        for (int j = 0; j < 4; ++j) {
          int row = rb * 16 + hi * 4 + j;
          float sig = 1.0f / (1.0f + __expf(-(acc2[rb][cb][j] + bs)));
          sel[row * 256 + ((n >> 3) ^ (row & 7)) * 8 + (n & 7)] = (short)pack2(sig, 0.f);
        }
    }
    __syncthreads();
    // sel GEMM: waves 0,1 -> 16 users each, all 64 slots (B = W3T from L2)
    if (wid < 2) {
      f32x4 acc3[4] = {};
      #pragma unroll
      for (int ks = 0; ks < 8; ++ks) {
        int row = wid * 16 + lo;
        int ca = ks * 4 + hi;
        short8 af = *(const short8*)&sel[row * 256 + (ca ^ (row & 7)) * 8];
        #pragma unroll
        for (int cb = 0; cb < 4; ++cb) {
          short8 bf = *(const short8*)(W3T_s + (size_t)(cb * 16 + lo) * HD + ks * 32 + hi * 8);
          acc3[cb] = __builtin_amdgcn_mfma_f32_16x16x32_bf16(af, bf, acc3[cb], 0, 0, 0);
        }
      }
      float sb3n[4];
      #pragma unroll
      for (int cb = 0; cb < 4; ++cb) sb3n[cb] = sb3[cb * 16 + lo];
      const int ubase = u0 + wid * 16 + hi * 4;
      #pragma unroll
      for (int j = 0; j < 4; ++j) {
        unsigned long long m = connS[ubase + j];
        float v[4]; bool ok[4];
        float mx = -INFINITY;
        #pragma unroll
        for (int cb = 0; cb < 4; ++cb) {
          int n = cb * 16 + lo;
          ok[cb] = (m >> n) & 1ull;
          v[cb] = ok[cb] ? (acc3[cb][j] + sb3n[cb]) : -INFINITY;
          mx = fmaxf(mx, v[cb]);
        }
        #pragma unroll
        for (int off = 1; off < 16; off <<= 1) mx = fmaxf(mx, __shfl_xor(mx, off, 64));
        float e[4], ssum = 0.f;
        #pragma unroll
        for (int cb = 0; cb < 4; ++cb) {
          e[cb] = ok[cb] ? __expf(v[cb] - mx) : 0.f;
          ssum += e[cb];
        }
        #pragma unroll
        for (int off = 1; off < 16; off <<= 1) ssum += __shfl_xor(ssum, off, 64);
        float iv = 1.0f / ssum;
        #pragma unroll
        for (int cb = 0; cb < 4; ++cb) {
          int n = cb * 16 + lo;
          out[(size_t)NUSER * 2 + (size_t)(ubase + j) * SSLOT + n] = e[cb] * iv;
        }
      }
    }
  }
}

// ---------------------------------------------------------------------------
extern "C" void kernel_launch(void* const* d_in, const int* in_sizes, int n_in,
                              void* d_out, int out_size, void* d_ws, size_t ws_size,
                              hipStream_t stream) {
  const float* x_user   = (const float*)d_in[0];
  const float* x_server = (const float*)d_in[1];
  const int*   dst_u2s  = (const int*)d_in[3];
  const int*   dst_u2u  = (const int*)d_in[5];
  const float* oW1 = (const float*)d_in[6];
  const float* ob1 = (const float*)d_in[7];
  const float* oW2 = (const float*)d_in[8];
  const float* ob2 = (const float*)d_in[9];
  const float* oW3 = (const float*)d_in[10];
  const float* ob3 = (const float*)d_in[11];
  const float* sW1 = (const float*)d_in[12];
  const float* sb1 = (const float*)d_in[13];
  const float* sW2 = (const float*)d_in[14];
  const float* sb2 = (const float*)d_in[15];
  const float* sW3 = (const float*)d_in[16];
  const float* sb3 = (const float*)d_in[17];

  char* ws = (char*)d_ws;
  unsigned long long* connS = (unsigned long long*)(ws + 0);          // 128 KB
  unsigned short* MSU  = (unsigned short*)(ws + 131072);              // 10.0 MB
  __hip_bfloat16* P_o  = (__hip_bfloat16*)(ws + 10616832);            // 2 MB
  __hip_bfloat16* P_s  = (__hip_bfloat16*)(ws + 12713984);            // 2 MB
  __hip_bfloat16* Q_o  = (__hip_bfloat16*)(ws + 14811136);            // 8 MB
  __hip_bfloat16* Q_s  = (__hip_bfloat16*)(ws + 23199744);            // 8 MB
  __hip_bfloat16* PQT_o = (__hip_bfloat16*)(ws + 31588352);           // 10 MB
  __hip_bfloat16* PQT_s = (__hip_bfloat16*)(ws + 42074112);           // 10 MB
  __hip_bfloat16* W2T_o = (__hip_bfloat16*)(ws + 52559872);           // 128 KB
  __hip_bfloat16* W2T_s = (__hip_bfloat16*)(ws + 52690944);           // 128 KB
  __hip_bfloat16* W3T_s = (__hip_bfloat16*)(ws + 52822016);           // 32 KB
  float* out = (float*)d_out;

  k_prep<<<320, 256, 0, stream>>>(dst_u2s, dst_u2u, oW2, sW2, sW3,
                                  connS, MSU, W2T_o, W2T_s, W3T_s);
  k_pq<<<dim3(KTOT, 8), 256, 0, stream>>>(x_user, x_server, oW1, sW1, P_o, P_s, Q_o, Q_s);
  k_tr<<<dim3(64, 2, 4), 256, 0, stream>>>(P_o, P_s, Q_o, Q_s, PQT_o, PQT_s);
  k_fused<<<dim3(512, 2), 256, 0, stream>>>(MSU, PQT_o, PQT_s, ob1, sb1,
                                            W2T_o, W2T_s, ob2, sb2,
                                            oW3, ob3, W3T_s, sb3, connS, out);
}

// Round 8
// 65.637 us; speedup vs baseline: 1.4081x; 1.4081x over previous
//
#include <hip/hip_runtime.h>
#include <hip/hip_bf16.h>
#include <math.h>
#include <cstdint>

#define NUSER 16384   // B*U
#define BB    64
#define UU    256
#define SSLOT 64
#define HD    256
#define DEGS  8
#define DEGU  16
#define PLROW 136     // shorts per LDS panel row (272 B): 128 cols + 8 pad

typedef __attribute__((ext_vector_type(8))) short short8;
typedef __attribute__((ext_vector_type(4))) float f32x4;

static __device__ __forceinline__ __hip_bfloat16 f2b(float x) { return __float2bfloat16(x); }
static __device__ __forceinline__ float uf(unsigned u) { return __uint_as_float(u); }
static __device__ __forceinline__ unsigned pack2(float x, float y) {
  union { __hip_bfloat16 h[2]; unsigned u; } cv;
  cv.h[0] = f2b(x); cv.h[1] = f2b(y);
  return cv.u;
}
static __device__ __forceinline__ void acc8(float4& a, uint2 v) {
  a.x += uf(v.x << 16); a.y += uf(v.x & 0xFFFF0000u);
  a.z += uf(v.y << 16); a.w += uf(v.y & 0xFFFF0000u);
}

// ---------------------------------------------------------------------------
// K1: prep. blocks 0..63: connS + dedup'd edge tables (slot*17, dup->zero row).
//           blocks 64..319: weight transposes to bf16.
// ---------------------------------------------------------------------------
__global__ __launch_bounds__(256) void k_prep(
    const int* __restrict__ dst_u2s, const int* __restrict__ dst_u2u,
    const float* __restrict__ oW2, const float* __restrict__ sW2,
    const float* __restrict__ sW3,
    unsigned long long* __restrict__ connS,
    unsigned short* __restrict__ pslots, unsigned short* __restrict__ qslots,
    __hip_bfloat16* __restrict__ W2T_o, __hip_bfloat16* __restrict__ W2T_s,
    __hip_bfloat16* __restrict__ W3T_s) {
  const int blk = blockIdx.x, t = threadIdx.x;
  if (blk < 64) {
    const int u = blk * 256 + t;
    unsigned long long ms = 0ull;
    unsigned short ps[DEGS];
    #pragma unroll
    for (int i = 0; i < DEGS; ++i) {
      int slot = dst_u2s[u * DEGS + i] & 63;
      ps[i] = (unsigned short)(((ms >> slot) & 1ull) ? 64 * 17 : slot * 17);
      ms |= 1ull << slot;
    }
    connS[u] = ms;
    *(uint4*)(pslots + (size_t)u * 8) = *(const uint4*)ps;
    unsigned long long m0 = 0, m1 = 0, m2 = 0, m3 = 0;
    unsigned short qs[DEGU];
    #pragma unroll
    for (int i = 0; i < DEGU; ++i) {
      int slot = dst_u2u[u * DEGU + i] & 255;
      unsigned long long bit = 1ull << (slot & 63);
      int w = slot >> 6;
      unsigned long long cur = (w == 0) ? m0 : (w == 1) ? m1 : (w == 2) ? m2 : m3;
      qs[i] = (unsigned short)((cur & bit) ? 256 * 17 : slot * 17);
      if (w == 0) m0 |= bit; else if (w == 1) m1 |= bit; else if (w == 2) m2 |= bit; else m3 |= bit;
    }
    *(uint4*)(qslots + (size_t)u * 16)     = *(const uint4*)qs;
    *(uint4*)(qslots + (size_t)u * 16 + 8) = *(const uint4*)(qs + 8);
  } else {
    const int n = blk - 64;
    W2T_o[n * HD + t] = f2b(oW2[t * HD + n]);
    W2T_s[n * HD + t] = f2b(sW2[t * HD + n]);
    if (n < SSLOT) W3T_s[n * HD + t] = f2b(sW3[t * SSLOT + n]);
  }
}

// ---------------------------------------------------------------------------
// K2: per-slot partial layer-1 products, bf16. grid (320 slots, 8 b-chunks).
// ---------------------------------------------------------------------------
__global__ __launch_bounds__(256) void k_pq(
    const float* __restrict__ xu, const float* __restrict__ xs,
    const float* __restrict__ oW1, const float* __restrict__ sW1,
    __hip_bfloat16* __restrict__ P_o, __hip_bfloat16* __restrict__ P_s,
    __hip_bfloat16* __restrict__ Q_o, __hip_bfloat16* __restrict__ Q_s) {
  const int t = threadIdx.x;
  const int wg = blockIdx.x;            // 0..63 server slots, 64..319 user slots
  const int b0 = blockIdx.y * 8;
  __shared__ float lx[8 * 16];
  const bool isS = wg < SSLOT;
  const int slot = isS ? wg : wg - SSLOT;
  if (t < 8 * 16) {
    int b = b0 + (t >> 4), d = t & 15;
    lx[t] = isS ? xs[(b * SSLOT + slot) * 16 + d] : xu[(b * UU + slot) * 16 + d];
  }
  __syncthreads();
  float wo[16], wsv[16];
  const int rbase = isS ? slot * 16 : SSLOT * 16 + slot * 16;
  #pragma unroll
  for (int d = 0; d < 16; ++d) {
    wo[d] = oW1[(rbase + d) * HD + t];
    wsv[d] = sW1[(rbase + d) * HD + t];
  }
  __hip_bfloat16* Ro = isS ? P_o : Q_o;
  __hip_bfloat16* Rs = isS ? P_s : Q_s;
  const int rows = isS ? SSLOT : UU;
  #pragma unroll
  for (int bi = 0; bi < 8; ++bi) {
    float ao = 0.f, as = 0.f;
    #pragma unroll
    for (int q = 0; q < 4; ++q) {
      float4 x4 = *(const float4*)&lx[bi * 16 + q * 4];
      ao = fmaf(x4.x, wo[q*4+0], ao); as = fmaf(x4.x, wsv[q*4+0], as);
      ao = fmaf(x4.y, wo[q*4+1], ao); as = fmaf(x4.y, wsv[q*4+1], as);
      ao = fmaf(x4.z, wo[q*4+2], ao); as = fmaf(x4.z, wsv[q*4+2], as);
      ao = fmaf(x4.w, wo[q*4+3], ao); as = fmaf(x4.w, wsv[q*4+3], as);
    }
    Ro[((b0 + bi) * rows + slot) * HD + t] = f2b(ao);
    Rs[((b0 + bi) * rows + slot) * HD + t] = f2b(as);
  }
}

// ---------------------------------------------------------------------------
// K3: h1 gather from an LDS-staged batch panel.
// grid (64 b, 2 mlp, 2 n-half), 512 thr. Panel: P 64x128 + Q 256x128 (+zero
// rows) = 87.6 KB. Each wave: 32 users, 2 at a time (half-wave = 1 user,
// lane covers 4 cols via ds_read_b64). Edge tables pre-deduped (dup->zero row).
// ---------------------------------------------------------------------------
__global__ __launch_bounds__(512) void k_h1(
    const unsigned short* __restrict__ pslots, const unsigned short* __restrict__ qslots,
    const __hip_bfloat16* __restrict__ P_o, const __hip_bfloat16* __restrict__ P_s,
    const __hip_bfloat16* __restrict__ Q_o, const __hip_bfloat16* __restrict__ Q_s,
    const float* __restrict__ ob1, const float* __restrict__ sb1,
    __hip_bfloat16* __restrict__ h1o, __hip_bfloat16* __restrict__ h1s) {
  const int b = blockIdx.x, mlp = blockIdx.y, nh = blockIdx.z;
  const int n0 = nh * 128;
  const int t = threadIdx.x;
  const __hip_bfloat16* P = mlp ? P_s : P_o;
  const __hip_bfloat16* Q = mlp ? Q_s : Q_o;
  const float* b1 = mlp ? sb1 : ob1;
  __hip_bfloat16* h1 = mlp ? h1s : h1o;

  __shared__ __align__(16) short lds[(65 + 257) * PLROW];
  short* Pl = lds;                       // 65 rows (64 + zero)
  short* Ql = lds + 65 * PLROW;          // 257 rows (256 + zero)

  // zero rows
  if (t < 68) {
    ((unsigned*)(Pl + 64 * PLROW))[t] = 0u;
    ((unsigned*)(Ql + 256 * PLROW))[t] = 0u;
  }
  // stage P half-panel: 1024 chunks of 16B
  #pragma unroll
  for (int i = 0; i < 2; ++i) {
    int c = t + i * 512;
    int s = c >> 4, kc = c & 15;
    *(short8*)&Pl[s * PLROW + kc * 8] =
        *(const short8*)(P + (size_t)(b * SSLOT + s) * HD + n0 + kc * 8);
  }
  // stage Q half-panel: 4096 chunks
  #pragma unroll
  for (int i = 0; i < 8; ++i) {
    int c = t + i * 512;
    int v = c >> 4, kc = c & 15;
    *(short8*)&Ql[v * PLROW + kc * 8] =
        *(const short8*)(Q + (size_t)(b * UU + v) * HD + n0 + kc * 8);
  }
  __syncthreads();

  const int wid = t >> 6, lane = t & 63;
  const int half = lane >> 5, li = lane & 31;
  const int li4 = li * 4;
  const int ubase = b * 256 + wid * 32;
  const float4 bias = *(const float4*)(b1 + n0 + li4);

  for (int i = 0; i < 16; ++i) {
    const int u = ubase + i * 2 + half;
    uint4 pe  = *(const uint4*)(pslots + (size_t)u * 8);
    uint4 qe0 = *(const uint4*)(qslots + (size_t)u * 16);
    uint4 qe1 = *(const uint4*)(qslots + (size_t)u * 16 + 8);
    unsigned pw[4] = {pe.x, pe.y, pe.z, pe.w};
    unsigned qw[8] = {qe0.x, qe0.y, qe0.z, qe0.w, qe1.x, qe1.y, qe1.z, qe1.w};
    float4 a = bias;
    #pragma unroll
    for (int j = 0; j < 4; ++j) {
      int r0 = pw[j] & 0xFFFF, r1 = pw[j] >> 16;     // already slot*17
      uint2 v0 = *(const uint2*)&Pl[(r0 << 3) + li4];
      uint2 v1 = *(const uint2*)&Pl[(r1 << 3) + li4];
      acc8(a, v0); acc8(a, v1);
    }
    #pragma unroll
    for (int j = 0; j < 8; ++j) {
      int r0 = qw[j] & 0xFFFF, r1 = qw[j] >> 16;
      uint2 v0 = *(const uint2*)&Ql[(r0 << 3) + li4];
      uint2 v1 = *(const uint2*)&Ql[(r1 << 3) + li4];
      acc8(a, v0); acc8(a, v1);
    }
    uint2 o;
    o.x = pack2(fmaxf(a.x, 0.f), fmaxf(a.y, 0.f));
    o.y = pack2(fmaxf(a.z, 0.f), fmaxf(a.w, 0.f));
    *(uint2*)(h1 + (size_t)u * HD + n0 + li4) = o;
  }
}

// ---------------------------------------------------------------------------
// K4: layer-2 GEMM + heads. grid (512 u-tiles of 32, 2 mlps), 256 thr.
// As 32x256 swizzled (16 KB); W2T staged per-kstep into Bs[256][72] padded
// rows (36 KB, 2-way-free ds_read_b128). part/sel alias As. 52 KB -> 3/CU.
// ---------------------------------------------------------------------------
__global__ __launch_bounds__(256) void k_heads(
    const __hip_bfloat16* __restrict__ h1o, const __hip_bfloat16* __restrict__ h1s,
    const __hip_bfloat16* __restrict__ W2T_o, const __hip_bfloat16* __restrict__ W2T_s,
    const float* __restrict__ ob2, const float* __restrict__ sb2,
    const float* __restrict__ oW3, const float* __restrict__ ob3,
    const __hip_bfloat16* __restrict__ W3T_s, const float* __restrict__ sb3,
    const unsigned long long* __restrict__ connS,
    float* __restrict__ out) {
  const int mlp = blockIdx.y;
  const int x = blockIdx.x;
  const int blk = (x & 7) * 64 + (x >> 3);      // XCD-affine, bijective
  const int u0 = blk * 32;
  const int t = threadIdx.x, lane = t & 63, wid = t >> 6;
  const int lo = lane & 15, hi = lane >> 4;

  const __hip_bfloat16* A   = mlp ? h1s : h1o;
  const __hip_bfloat16* W2T = mlp ? W2T_s : W2T_o;
  const float* b2 = mlp ? sb2 : ob2;

  __shared__ __align__(16) char lds[16384 + 36864];
  short* As = (short*)lds;               // 32 x 256, chunk-swizzled
  short* Bs = (short*)(lds + 16384);     // 256 x 72 (padded rows)
  float* part = (float*)lds;             // alias (mlp==0, after barrier)

  // stage A tile (1024 chunks)
  #pragma unroll
  for (int i = 0; i < 4; ++i) {
    int c = t + i * 256;
    int row = c >> 5, cc = c & 31;
    *(short8*)&As[row * 256 + (cc ^ (row & 7)) * 8] =
        *(const short8*)(A + (size_t)(u0 + row) * HD + cc * 8);
  }
  __syncthreads();

  f32x4 acc2[2][4] = {};
  for (int ks = 0; ks < 8; ++ks) {
    if (ks) __syncthreads();             // protect Bs reuse
    #pragma unroll
    for (int i = 0; i < 4; ++i) {        // stage Bs: 1024 chunks
      int c = t + i * 256;
      int n = c >> 2, kc = c & 3;
      *(short8*)&Bs[n * 72 + kc * 8] =
          *(const short8*)(W2T + (size_t)n * HD + ks * 32 + kc * 8);
    }
    __syncthreads();
    short8 af[2], bf[4];
    #pragma unroll
    for (int rb = 0; rb < 2; ++rb) {
      int row = rb * 16 + lo;
      int ca = ks * 4 + hi;
      af[rb] = *(const short8*)&As[row * 256 + (ca ^ (row & 7)) * 8];
    }
    #pragma unroll
    for (int cb = 0; cb < 4; ++cb) {
      int n = wid * 64 + cb * 16 + lo;
      bf[cb] = *(const short8*)&Bs[n * 72 + hi * 8];
    }
    #pragma unroll
    for (int rb = 0; rb < 2; ++rb)
      #pragma unroll
      for (int cb = 0; cb < 4; ++cb)
        acc2[rb][cb] = __builtin_amdgcn_mfma_f32_16x16x32_bf16(af[rb], bf[cb], acc2[rb][cb], 0, 0, 0);
  }
  __syncthreads();                        // As reads done -> reuse as part/sel

  if (mlp == 0) {
    float p0[2][4] = {}, p1[2][4] = {};
    #pragma unroll
    for (int cb = 0; cb < 4; ++cb) {
      int n = wid * 64 + cb * 16 + lo;
      float bs = b2[n], w0 = oW3[2 * n], w1 = oW3[2 * n + 1];
      #pragma unroll
      for (int rb = 0; rb < 2; ++rb)
        #pragma unroll
        for (int j = 0; j < 4; ++j) {
          float sig = 1.0f / (1.0f + __expf(-(acc2[rb][cb][j] + bs)));
          p0[rb][j] = fmaf(sig, w0, p0[rb][j]);
          p1[rb][j] = fmaf(sig, w1, p1[rb][j]);
        }
    }
    #pragma unroll
    for (int rb = 0; rb < 2; ++rb)
      #pragma unroll
      for (int j = 0; j < 4; ++j) {
        #pragma unroll
        for (int off = 1; off < 16; off <<= 1) {
          p0[rb][j] += __shfl_xor(p0[rb][j], off, 64);
          p1[rb][j] += __shfl_xor(p1[rb][j], off, 64);
        }
        if (lo == 0) {
          int row = rb * 16 + hi * 4 + j;
          part[wid * 64 + row * 2 + 0] = p0[rb][j];
          part[wid * 64 + row * 2 + 1] = p1[rb][j];
        }
      }
    __syncthreads();
    if (t < 32) {
      float q0 = part[t * 2] + part[64 + t * 2] + part[128 + t * 2] + part[192 + t * 2] + ob3[0];
      float q1 = part[t * 2 + 1] + part[64 + t * 2 + 1] + part[128 + t * 2 + 1] + part[192 + t * 2 + 1] + ob3[1];
      float m2 = fmaxf(q0, q1);
      float e0 = __expf(q0 - m2), e1 = __expf(q1 - m2);
      float iv = 1.0f / (e0 + e1);
      float2 r; r.x = e0 * iv; r.y = e1 * iv;
      *(float2*)(out + (size_t)(u0 + t) * 2) = r;
    }
  } else {
    short* sel = As;
    #pragma unroll
    for (int cb = 0; cb < 4; ++cb) {
      int n = wid * 64 + cb * 16 + lo;
      float bs = b2[n];
      #pragma unroll
      for (int rb = 0; rb < 2; ++rb)
        #pragma unroll
        for (int j = 0; j < 4; ++j) {
          int row = rb * 16 + hi * 4 + j;
          float sig = 1.0f / (1.0f + __expf(-(acc2[rb][cb][j] + bs)));
          sel[row * 256 + ((n >> 3) ^ (row & 7)) * 8 + (n & 7)] = (short)pack2(sig, 0.f);
        }
    }
    __syncthreads();
    if (wid < 2) {
      f32x4 acc3[4] = {};
      #pragma unroll
      for (int ks = 0; ks < 8; ++ks) {
        int row = wid * 16 + lo;
        int ca = ks * 4 + hi;
        short8 af = *(const short8*)&sel[row * 256 + (ca ^ (row & 7)) * 8];
        #pragma unroll
        for (int cb = 0; cb < 4; ++cb) {
          short8 bf = *(const short8*)(W3T_s + (size_t)(cb * 16 + lo) * HD + ks * 32 + hi * 8);
          acc3[cb] = __builtin_amdgcn_mfma_f32_16x16x32_bf16(af, bf, acc3[cb], 0, 0, 0);
        }
      }
      float sb3n[4];
      #pragma unroll
      for (int cb = 0; cb < 4; ++cb) sb3n[cb] = sb3[cb * 16 + lo];
      const int ubase = u0 + wid * 16 + hi * 4;
      #pragma unroll
      for (int j = 0; j < 4; ++j) {
        unsigned long long m = connS[ubase + j];
        float v[4]; bool ok[4];
        float mx = -INFINITY;
        #pragma unroll
        for (int cb = 0; cb < 4; ++cb) {
          int n = cb * 16 + lo;
          ok[cb] = (m >> n) & 1ull;
          v[cb] = ok[cb] ? (acc3[cb][j] + sb3n[cb]) : -INFINITY;
          mx = fmaxf(mx, v[cb]);
        }
        #pragma unroll
        for (int off = 1; off < 16; off <<= 1) mx = fmaxf(mx, __shfl_xor(mx, off, 64));
        float e[4], ssum = 0.f;
        #pragma unroll
        for (int cb = 0; cb < 4; ++cb) {
          e[cb] = ok[cb] ? __expf(v[cb] - mx) : 0.f;
          ssum += e[cb];
        }
        #pragma unroll
        for (int off = 1; off < 16; off <<= 1) ssum += __shfl_xor(ssum, off, 64);
        float iv = 1.0f / ssum;
        #pragma unroll
        for (int cb = 0; cb < 4; ++cb) {
          int n = cb * 16 + lo;
          out[(size_t)NUSER * 2 + (size_t)(ubase + j) * SSLOT + n] = e[cb] * iv;
        }
      }
    }
  }
}

// ---------------------------------------------------------------------------
extern "C" void kernel_launch(void* const* d_in, const int* in_sizes, int n_in,
                              void* d_out, int out_size, void* d_ws, size_t ws_size,
                              hipStream_t stream) {
  const float* x_user   = (const float*)d_in[0];
  const float* x_server = (const float*)d_in[1];
  const int*   dst_u2s  = (const int*)d_in[3];
  const int*   dst_u2u  = (const int*)d_in[5];
  const float* oW1 = (const float*)d_in[6];
  const float* ob1 = (const float*)d_in[7];
  const float* oW2 = (const float*)d_in[8];
  const float* ob2 = (const float*)d_in[9];
  const float* oW3 = (const float*)d_in[10];
  const float* ob3 = (const float*)d_in[11];
  const float* sW1 = (const float*)d_in[12];
  const float* sb1 = (const float*)d_in[13];
  const float* sW2 = (const float*)d_in[14];
  const float* sb2 = (const float*)d_in[15];
  const float* sW3 = (const float*)d_in[16];
  const float* sb3 = (const float*)d_in[17];

  char* ws = (char*)d_ws;
  unsigned long long* connS  = (unsigned long long*)(ws + 0);        // 128 KB
  unsigned short*     pslots = (unsigned short*)(ws + 131072);       // 256 KB
  unsigned short*     qslots = (unsigned short*)(ws + 393216);       // 512 KB
  __hip_bfloat16* P_o  = (__hip_bfloat16*)(ws + 917504);             // 2 MB
  __hip_bfloat16* P_s  = (__hip_bfloat16*)(ws + 3014656);            // 2 MB
  __hip_bfloat16* Q_o  = (__hip_bfloat16*)(ws + 5111808);            // 8 MB
  __hip_bfloat16* Q_s  = (__hip_bfloat16*)(ws + 13500416);           // 8 MB
  __hip_bfloat16* h1o  = (__hip_bfloat16*)(ws + 21889024);           // 8 MB
  __hip_bfloat16* h1s  = (__hip_bfloat16*)(ws + 30277632);           // 8 MB
  __hip_bfloat16* W2T_o = (__hip_bfloat16*)(ws + 38666240);          // 128 KB
  __hip_bfloat16* W2T_s = (__hip_bfloat16*)(ws + 38797312);          // 128 KB
  __hip_bfloat16* W3T_s = (__hip_bfloat16*)(ws + 38928384);          // 32 KB
  float* out = (float*)d_out;

  k_prep<<<320, 256, 0, stream>>>(dst_u2s, dst_u2u, oW2, sW2, sW3,
                                  connS, pslots, qslots, W2T_o, W2T_s, W3T_s);
  k_pq<<<dim3(SSLOT + UU, 8), 256, 0, stream>>>(x_user, x_server, oW1, sW1,
                                                P_o, P_s, Q_o, Q_s);
  k_h1<<<dim3(BB, 2, 2), 512, 0, stream>>>(pslots, qslots, P_o, P_s, Q_o, Q_s,
                                           ob1, sb1, h1o, h1s);
  k_heads<<<dim3(512, 2), 256, 0, stream>>>(h1o, h1s, W2T_o, W2T_s, ob2, sb2,
                                            oW3, ob3, W3T_s, sb3, connS, out);
}

// Round 9
// 61.013 us; speedup vs baseline: 1.5148x; 1.0758x over previous
//
#include <hip/hip_runtime.h>
#include <hip/hip_bf16.h>
#include <math.h>
#include <cstdint>

#define NUSER 16384   // B*U
#define BB    64
#define UU    256
#define SSLOT 64
#define HD    256
#define KTOT  320
#define DEGS  8
#define DEGU  16

typedef __attribute__((ext_vector_type(8))) short short8;
typedef __attribute__((ext_vector_type(4))) float f32x4;

static __device__ __forceinline__ __hip_bfloat16 f2b(float x) { return __float2bfloat16(x); }
static __device__ __forceinline__ unsigned pack2(float x, float y) {
  union { __hip_bfloat16 h[2]; unsigned u; } cv;
  cv.h[0] = f2b(x); cv.h[1] = f2b(y);
  return cv.u;
}

// ---------------------------------------------------------------------------
// K1: merged prep + per-slot layer-1 products.
// y==0, x<64   : connS + 320-bit mask words MSUW[u][10] (u32)
// y==0, x>=64  : weight transposes to bf16
// y>=1         : k_pq body, 8 batches per block
// ---------------------------------------------------------------------------
__global__ __launch_bounds__(256) void k_prep_pq(
    const int* __restrict__ dst_u2s, const int* __restrict__ dst_u2u,
    const float* __restrict__ oW2, const float* __restrict__ sW2,
    const float* __restrict__ sW3,
    const float* __restrict__ xu, const float* __restrict__ xs,
    const float* __restrict__ oW1, const float* __restrict__ sW1,
    unsigned long long* __restrict__ connS, unsigned* __restrict__ MSUW,
    __hip_bfloat16* __restrict__ W2T_o, __hip_bfloat16* __restrict__ W2T_s,
    __hip_bfloat16* __restrict__ W3T_s,
    __hip_bfloat16* __restrict__ P_o, __hip_bfloat16* __restrict__ P_s,
    __hip_bfloat16* __restrict__ Q_o, __hip_bfloat16* __restrict__ Q_s) {
  const int t = threadIdx.x;
  if (blockIdx.y == 0) {
    const int blk = blockIdx.x;
    if (blk < 64) {
      const int u = blk * 256 + t;
      unsigned long long ms = 0ull;
      #pragma unroll
      for (int i = 0; i < DEGS; ++i) ms |= 1ull << (dst_u2s[u * DEGS + i] & 63);
      connS[u] = ms;
      unsigned long long m0 = 0, m1 = 0, m2 = 0, m3 = 0;
      #pragma unroll
      for (int i = 0; i < DEGU; ++i) {
        int slot = dst_u2u[u * DEGU + i] & 255;
        unsigned long long bit = 1ull << (slot & 63);
        int w = slot >> 6;
        if (w == 0) m0 |= bit; else if (w == 1) m1 |= bit;
        else if (w == 2) m2 |= bit; else m3 |= bit;
      }
      unsigned* mw = MSUW + (size_t)u * 10;
      uint2* mw2 = (uint2*)mw;
      mw2[0] = make_uint2((unsigned)ms, (unsigned)(ms >> 32));
      mw2[1] = make_uint2((unsigned)m0, (unsigned)(m0 >> 32));
      mw2[2] = make_uint2((unsigned)m1, (unsigned)(m1 >> 32));
      mw2[3] = make_uint2((unsigned)m2, (unsigned)(m2 >> 32));
      mw2[4] = make_uint2((unsigned)m3, (unsigned)(m3 >> 32));
    } else {
      const int n = blk - 64;
      W2T_o[n * HD + t] = f2b(oW2[t * HD + n]);
      W2T_s[n * HD + t] = f2b(sW2[t * HD + n]);
      if (n < SSLOT) W3T_s[n * HD + t] = f2b(sW3[t * SSLOT + n]);
    }
    return;
  }
  // ---- pq body ----
  const int wg = blockIdx.x;            // 0..63 server slots, 64..319 user slots
  const int b0 = (blockIdx.y - 1) * 8;
  __shared__ float lx[8 * 16];
  const bool isS = wg < SSLOT;
  const int slot = isS ? wg : wg - SSLOT;
  if (t < 8 * 16) {
    int b = b0 + (t >> 4), d = t & 15;
    lx[t] = isS ? xs[(b * SSLOT + slot) * 16 + d] : xu[(b * UU + slot) * 16 + d];
  }
  __syncthreads();
  float wo[16], wsv[16];
  const int rbase = isS ? slot * 16 : SSLOT * 16 + slot * 16;
  #pragma unroll
  for (int d = 0; d < 16; ++d) {
    wo[d] = oW1[(rbase + d) * HD + t];
    wsv[d] = sW1[(rbase + d) * HD + t];
  }
  __hip_bfloat16* Ro = isS ? P_o : Q_o;
  __hip_bfloat16* Rs = isS ? P_s : Q_s;
  const int rows = isS ? SSLOT : UU;
  #pragma unroll
  for (int bi = 0; bi < 8; ++bi) {
    float ao = 0.f, as = 0.f;
    #pragma unroll
    for (int q = 0; q < 4; ++q) {
      float4 x4 = *(const float4*)&lx[bi * 16 + q * 4];
      ao = fmaf(x4.x, wo[q*4+0], ao); as = fmaf(x4.x, wsv[q*4+0], as);
      ao = fmaf(x4.y, wo[q*4+1], ao); as = fmaf(x4.y, wsv[q*4+1], as);
      ao = fmaf(x4.z, wo[q*4+2], ao); as = fmaf(x4.z, wsv[q*4+2], as);
      ao = fmaf(x4.w, wo[q*4+3], ao); as = fmaf(x4.w, wsv[q*4+3], as);
    }
    Ro[((b0 + bi) * rows + slot) * HD + t] = f2b(ao);
    Rs[((b0 + bi) * rows + slot) * HD + t] = f2b(as);
  }
}

// ---------------------------------------------------------------------------
// K2: transpose P,Q -> PQT[b][n][320] (n-major, k-contiguous). (round-6 code)
// ---------------------------------------------------------------------------
__global__ __launch_bounds__(256) void k_tr(
    const __hip_bfloat16* __restrict__ P_o, const __hip_bfloat16* __restrict__ P_s,
    const __hip_bfloat16* __restrict__ Q_o, const __hip_bfloat16* __restrict__ Q_s,
    __hip_bfloat16* __restrict__ PQT_o, __hip_bfloat16* __restrict__ PQT_s) {
  const int b = blockIdx.x, mlp = blockIdx.y, nc = blockIdx.z;
  const int n0 = nc * 64;
  const int t = threadIdx.x;
  const __hip_bfloat16* P = mlp ? P_s : P_o;
  const __hip_bfloat16* Q = mlp ? Q_s : Q_o;
  __hip_bfloat16* PQT = mlp ? PQT_s : PQT_o;
  __shared__ __align__(16) short lds[64 * 72];
  for (int kt = 0; kt < 5; ++kt) {
    const __hip_bfloat16* src = (kt == 0) ? (P + (size_t)(b * SSLOT) * HD)
                                          : (Q + (size_t)(b * UU + (kt - 1) * 64) * HD);
    const int kout = (kt == 0) ? 0 : 64 + (kt - 1) * 64;
    #pragma unroll
    for (int i = 0; i < 2; ++i) {
      int c = t + i * 256;
      int row = c >> 3, cc = c & 7;
      *(short8*)&lds[row * 72 + cc * 8] =
          *(const short8*)(src + (size_t)row * HD + n0 + cc * 8);
    }
    __syncthreads();
    #pragma unroll
    for (int i = 0; i < 2; ++i) {
      int c = t + i * 256;
      int nrow = c >> 3, kc = c & 7;
      short8 v;
      #pragma unroll
      for (int e = 0; e < 8; ++e) v[e] = lds[(kc * 8 + e) * 72 + nrow];
      *(short8*)(PQT + (size_t)(b * 256 + n0 + nrow) * KTOT + kout + kc * 8) = v;
    }
    __syncthreads();
  }
}

// ---------------------------------------------------------------------------
// K3: h1 via mask-MFMA, both operands LDS-resident.
// grid (64 b, 2 mlp, 2 nh), 512 thr (8 waves, 2x: 4 user-rows x 2 col-halves).
// Panel: PQT rows [128 n][320 k] XOR-swizzled (80 KB). Masks: 2560 u32 (10 KB).
// A-fragments generated in-register from mask bits (1.0/0.0 bf16).
// ---------------------------------------------------------------------------
__global__ __launch_bounds__(512) void k_h1(
    const unsigned* __restrict__ MSUW,
    const __hip_bfloat16* __restrict__ PQT_o, const __hip_bfloat16* __restrict__ PQT_s,
    const float* __restrict__ ob1, const float* __restrict__ sb1,
    __hip_bfloat16* __restrict__ h1o, __hip_bfloat16* __restrict__ h1s) {
  const int b = blockIdx.x, mlp = blockIdx.y, nh = blockIdx.z;
  const int n0 = nh * 128;
  const int t = threadIdx.x;
  const __hip_bfloat16* PQT = mlp ? PQT_s : PQT_o;
  const float* b1 = mlp ? sb1 : ob1;
  __hip_bfloat16* h1 = mlp ? h1s : h1o;

  __shared__ __align__(16) short pan[128 * KTOT];   // 80 KB
  __shared__ __align__(16) unsigned mskL[256 * 10]; // 10 KB

  // stage panel: thread covers row r = t>>2, chunks (t&3)+4i (i<10)
  {
    const int r = t >> 2;
    const int c4 = t & 3;
    const __hip_bfloat16* src = PQT + (size_t)(b * 256 + n0 + r) * KTOT;
    #pragma unroll
    for (int i = 0; i < 10; ++i) {
      int cc = c4 + 4 * i;
      *(short8*)&pan[r * KTOT + ((cc ^ (r & 7)) * 8)] = *(const short8*)(src + cc * 8);
    }
  }
  // stage mask words (1280 uint2)
  {
    const uint2* g = (const uint2*)(MSUW + (size_t)b * 2560);
    uint2* l = (uint2*)mskL;
    l[t] = g[t];
    l[t + 512] = g[t + 512];
    if (t < 256) l[t + 1024] = g[t + 1024];
  }
  __syncthreads();

  const int lane = t & 63, w = t >> 6;
  const int wr = w >> 1, wc = w & 1;   // users wr*64.., cols wc*64..
  const int lo = lane & 15, hi = lane >> 4;
  f32x4 acc[4][4] = {};
  #pragma unroll
  for (int kt = 0; kt < 10; ++kt) {
    short8 af[4], bf[4];
    #pragma unroll
    for (int rb = 0; rb < 4; ++rb) {
      int ul = wr * 64 + rb * 16 + lo;
      unsigned m = mskL[ul * 10 + kt];
      unsigned by = (m >> (hi * 8)) & 0xFFu;
      union { unsigned u[4]; short8 s; } cv;
      cv.u[0] = ((by & 1u)   ? 0x3F80u : 0u) | ((by & 2u)   ? 0x3F800000u : 0u);
      cv.u[1] = ((by & 4u)   ? 0x3F80u : 0u) | ((by & 8u)   ? 0x3F800000u : 0u);
      cv.u[2] = ((by & 16u)  ? 0x3F80u : 0u) | ((by & 32u)  ? 0x3F800000u : 0u);
      cv.u[3] = ((by & 64u)  ? 0x3F80u : 0u) | ((by & 128u) ? 0x3F800000u : 0u);
      af[rb] = cv.s;
    }
    #pragma unroll
    for (int cb = 0; cb < 4; ++cb) {
      int n = wc * 64 + cb * 16 + lo;
      int cc = kt * 4 + hi;
      bf[cb] = *(const short8*)&pan[n * KTOT + ((cc ^ (n & 7)) * 8)];
    }
    #pragma unroll
    for (int rb = 0; rb < 4; ++rb)
      #pragma unroll
      for (int cb = 0; cb < 4; ++cb)
        acc[rb][cb] = __builtin_amdgcn_mfma_f32_16x16x32_bf16(af[rb], bf[cb], acc[rb][cb], 0, 0, 0);
  }
  // epilogue: bias + relu -> h1 global (bf16)
  #pragma unroll
  for (int cb = 0; cb < 4; ++cb) {
    int n = wc * 64 + cb * 16 + lo;
    float bv = b1[n0 + n];
    #pragma unroll
    for (int rb = 0; rb < 4; ++rb) {
      #pragma unroll
      for (int j = 0; j < 4; ++j) {
        int u = b * 256 + wr * 64 + rb * 16 + hi * 4 + j;
        h1[(size_t)u * HD + n0 + n] = f2b(fmaxf(acc[rb][cb][j] + bv, 0.f));
      }
    }
  }
}

// ---------------------------------------------------------------------------
// K4: layer-2 GEMM + heads (round-8 code, unchanged).
// ---------------------------------------------------------------------------
__global__ __launch_bounds__(256) void k_heads(
    const __hip_bfloat16* __restrict__ h1o, const __hip_bfloat16* __restrict__ h1s,
    const __hip_bfloat16* __restrict__ W2T_o, const __hip_bfloat16* __restrict__ W2T_s,
    const float* __restrict__ ob2, const float* __restrict__ sb2,
    const float* __restrict__ oW3, const float* __restrict__ ob3,
    const __hip_bfloat16* __restrict__ W3T_s, const float* __restrict__ sb3,
    const unsigned long long* __restrict__ connS,
    float* __restrict__ out) {
  const int mlp = blockIdx.y;
  const int x = blockIdx.x;
  const int blk = (x & 7) * 64 + (x >> 3);
  const int u0 = blk * 32;
  const int t = threadIdx.x, lane = t & 63, wid = t >> 6;
  const int lo = lane & 15, hi = lane >> 4;

  const __hip_bfloat16* A   = mlp ? h1s : h1o;
  const __hip_bfloat16* W2T = mlp ? W2T_s : W2T_o;
  const float* b2 = mlp ? sb2 : ob2;

  __shared__ __align__(16) char lds[16384 + 36864];
  short* As = (short*)lds;
  short* Bs = (short*)(lds + 16384);
  float* part = (float*)lds;

  #pragma unroll
  for (int i = 0; i < 4; ++i) {
    int c = t + i * 256;
    int row = c >> 5, cc = c & 31;
    *(short8*)&As[row * 256 + (cc ^ (row & 7)) * 8] =
        *(const short8*)(A + (size_t)(u0 + row) * HD + cc * 8);
  }
  __syncthreads();

  f32x4 acc2[2][4] = {};
  for (int ks = 0; ks < 8; ++ks) {
    if (ks) __syncthreads();
    #pragma unroll
    for (int i = 0; i < 4; ++i) {
      int c = t + i * 256;
      int n = c >> 2, kc = c & 3;
      *(short8*)&Bs[n * 72 + kc * 8] =
          *(const short8*)(W2T + (size_t)n * HD + ks * 32 + kc * 8);
    }
    __syncthreads();
    short8 af[2], bf[4];
    #pragma unroll
    for (int rb = 0; rb < 2; ++rb) {
      int row = rb * 16 + lo;
      int ca = ks * 4 + hi;
      af[rb] = *(const short8*)&As[row * 256 + (ca ^ (row & 7)) * 8];
    }
    #pragma unroll
    for (int cb = 0; cb < 4; ++cb) {
      int n = wid * 64 + cb * 16 + lo;
      bf[cb] = *(const short8*)&Bs[n * 72 + hi * 8];
    }
    #pragma unroll
    for (int rb = 0; rb < 2; ++rb)
      #pragma unroll
      for (int cb = 0; cb < 4; ++cb)
        acc2[rb][cb] = __builtin_amdgcn_mfma_f32_16x16x32_bf16(af[rb], bf[cb], acc2[rb][cb], 0, 0, 0);
  }
  __syncthreads();

  if (mlp == 0) {
    float p0[2][4] = {}, p1[2][4] = {};
    #pragma unroll
    for (int cb = 0; cb < 4; ++cb) {
      int n = wid * 64 + cb * 16 + lo;
      float bs = b2[n], w0 = oW3[2 * n], w1 = oW3[2 * n + 1];
      #pragma unroll
      for (int rb = 0; rb < 2; ++rb)
        #pragma unroll
        for (int j = 0; j < 4; ++j) {
          float sig = 1.0f / (1.0f + __expf(-(acc2[rb][cb][j] + bs)));
          p0[rb][j] = fmaf(sig, w0, p0[rb][j]);
          p1[rb][j] = fmaf(sig, w1, p1[rb][j]);
        }
    }
    #pragma unroll
    for (int rb = 0; rb < 2; ++rb)
      #pragma unroll
      for (int j = 0; j < 4; ++j) {
        #pragma unroll
        for (int off = 1; off < 16; off <<= 1) {
          p0[rb][j] += __shfl_xor(p0[rb][j], off, 64);
          p1[rb][j] += __shfl_xor(p1[rb][j], off, 64);
        }
        if (lo == 0) {
          int row = rb * 16 + hi * 4 + j;
          part[wid * 64 + row * 2 + 0] = p0[rb][j];
          part[wid * 64 + row * 2 + 1] = p1[rb][j];
        }
      }
    __syncthreads();
    if (t < 32) {
      float q0 = part[t * 2] + part[64 + t * 2] + part[128 + t * 2] + part[192 + t * 2] + ob3[0];
      float q1 = part[t * 2 + 1] + part[64 + t * 2 + 1] + part[128 + t * 2 + 1] + part[192 + t * 2 + 1] + ob3[1];
      float m2 = fmaxf(q0, q1);
      float e0 = __expf(q0 - m2), e1 = __expf(q1 - m2);
      float iv = 1.0f / (e0 + e1);
      float2 r; r.x = e0 * iv; r.y = e1 * iv;
      *(float2*)(out + (size_t)(u0 + t) * 2) = r;
    }
  } else {
    short* sel = As;
    #pragma unroll
    for (int cb = 0; cb < 4; ++cb) {
      int n = wid * 64 + cb * 16 + lo;
      float bs = b2[n];
      #pragma unroll
      for (int rb = 0; rb < 2; ++rb)
        #pragma unroll
        for (int j = 0; j < 4; ++j) {
          int row = rb * 16 + hi * 4 + j;
          float sig = 1.0f / (1.0f + __expf(-(acc2[rb][cb][j] + bs)));
          sel[row * 256 + ((n >> 3) ^ (row & 7)) * 8 + (n & 7)] = (short)pack2(sig, 0.f);
        }
    }
    __syncthreads();
    if (wid < 2) {
      f32x4 acc3[4] = {};
      #pragma unroll
      for (int ks = 0; ks < 8; ++ks) {
        int row = wid * 16 + lo;
        int ca = ks * 4 + hi;
        short8 af = *(const short8*)&sel[row * 256 + (ca ^ (row & 7)) * 8];
        #pragma unroll
        for (int cb = 0; cb < 4; ++cb) {
          short8 bf = *(const short8*)(W3T_s + (size_t)(cb * 16 + lo) * HD + ks * 32 + hi * 8);
          acc3[cb] = __builtin_amdgcn_mfma_f32_16x16x32_bf16(af, bf, acc3[cb], 0, 0, 0);
        }
      }
      float sb3n[4];
      #pragma unroll
      for (int cb = 0; cb < 4; ++cb) sb3n[cb] = sb3[cb * 16 + lo];
      const int ubase = u0 + wid * 16 + hi * 4;
      #pragma unroll
      for (int j = 0; j < 4; ++j) {
        unsigned long long m = connS[ubase + j];
        float v[4]; bool ok[4];
        float mx = -INFINITY;
        #pragma unroll
        for (int cb = 0; cb < 4; ++cb) {
          int n = cb * 16 + lo;
          ok[cb] = (m >> n) & 1ull;
          v[cb] = ok[cb] ? (acc3[cb][j] + sb3n[cb]) : -INFINITY;
          mx = fmaxf(mx, v[cb]);
        }
        #pragma unroll
        for (int off = 1; off < 16; off <<= 1) mx = fmaxf(mx, __shfl_xor(mx, off, 64));
        float e[4], ssum = 0.f;
        #pragma unroll
        for (int cb = 0; cb < 4; ++cb) {
          e[cb] = ok[cb] ? __expf(v[cb] - mx) : 0.f;
          ssum += e[cb];
        }
        #pragma unroll
        for (int off = 1; off < 16; off <<= 1) ssum += __shfl_xor(ssum, off, 64);
        float iv = 1.0f / ssum;
        #pragma unroll
        for (int cb = 0; cb < 4; ++cb) {
          int n = cb * 16 + lo;
          out[(size_t)NUSER * 2 + (size_t)(ubase + j) * SSLOT + n] = e[cb] * iv;
        }
      }
    }
  }
}

// ---------------------------------------------------------------------------
extern "C" void kernel_launch(void* const* d_in, const int* in_sizes, int n_in,
                              void* d_out, int out_size, void* d_ws, size_t ws_size,
                              hipStream_t stream) {
  const float* x_user   = (const float*)d_in[0];
  const float* x_server = (const float*)d_in[1];
  const int*   dst_u2s  = (const int*)d_in[3];
  const int*   dst_u2u  = (const int*)d_in[5];
  const float* oW1 = (const float*)d_in[6];
  const float* ob1 = (const float*)d_in[7];
  const float* oW2 = (const float*)d_in[8];
  const float* ob2 = (const float*)d_in[9];
  const float* oW3 = (const float*)d_in[10];
  const float* ob3 = (const float*)d_in[11];
  const float* sW1 = (const float*)d_in[12];
  const float* sb1 = (const float*)d_in[13];
  const float* sW2 = (const float*)d_in[14];
  const float* sb2 = (const float*)d_in[15];
  const float* sW3 = (const float*)d_in[16];
  const float* sb3 = (const float*)d_in[17];

  char* ws = (char*)d_ws;
  unsigned long long* connS = (unsigned long long*)(ws + 0);         // 128 KB
  unsigned*       MSUW = (unsigned*)(ws + 131072);                   // 640 KB
  __hip_bfloat16* P_o  = (__hip_bfloat16*)(ws + 786432);             // 2 MB
  __hip_bfloat16* P_s  = (__hip_bfloat16*)(ws + 2883584);            // 2 MB
  __hip_bfloat16* Q_o  = (__hip_bfloat16*)(ws + 4980736);            // 8 MB
  __hip_bfloat16* Q_s  = (__hip_bfloat16*)(ws + 13369344);           // 8 MB
  __hip_bfloat16* PQT_o = (__hip_bfloat16*)(ws + 21757952);          // 10 MB
  __hip_bfloat16* PQT_s = (__hip_bfloat16*)(ws + 32243712);          // 10 MB
  __hip_bfloat16* h1o  = (__hip_bfloat16*)(ws + 42729472);           // 8 MB
  __hip_bfloat16* h1s  = (__hip_bfloat16*)(ws + 51118080);           // 8 MB
  __hip_bfloat16* W2T_o = (__hip_bfloat16*)(ws + 59506688);          // 128 KB
  __hip_bfloat16* W2T_s = (__hip_bfloat16*)(ws + 59637760);          // 128 KB
  __hip_bfloat16* W3T_s = (__hip_bfloat16*)(ws + 59768832);          // 32 KB
  float* out = (float*)d_out;

  k_prep_pq<<<dim3(320, 9), 256, 0, stream>>>(
      dst_u2s, dst_u2u, oW2, sW2, sW3, x_user, x_server, oW1, sW1,
      connS, MSUW, W2T_o, W2T_s, W3T_s, P_o, P_s, Q_o, Q_s);
  k_tr<<<dim3(64, 2, 4), 256, 0, stream>>>(P_o, P_s, Q_o, Q_s, PQT_o, PQT_s);
  k_h1<<<dim3(64, 2, 2), 512, 0, stream>>>(MSUW, PQT_o, PQT_s, ob1, sb1, h1o, h1s);
  k_heads<<<dim3(512, 2), 256, 0, stream>>>(h1o, h1s, W2T_o, W2T_s, ob2, sb2,
                                            oW3, ob3, W3T_s, sb3, connS, out);
}